// Round 2
// baseline (805.806 us; speedup 1.0000x reference)
//
#include <hip/hip_runtime.h>

// SSA pipeline, f32, round 2.
// Shapes: T=4 B=8 N=512 D=512 H=8 DH=64.  M = T*B*N = 16384 rows per GEMM.
// ws: 3 buffers of T*B*N*D f32 (33.5 MB each, 100.7 MB total).

#define T_  4
#define B_  8
#define N_  512
#define D_  512
#define H_  8
#define DH_ 64
#define M_  (T_ * B_ * N_)            // 16384
#define E_  ((size_t)B_ * N_ * D_)   // elements per time slab = 2097152

__device__ __forceinline__ float lif_step(float& vmem, float u) {
    vmem += (u - vmem) * 0.5f;                 // TAU = 2.0 (exact *0.5)
    float spk = (vmem >= 1.0f) ? 1.0f : 0.0f;  // forward heaviside
    vmem *= (1.0f - spk);                      // hard reset
    return spk;
}

// C[row,d] = bn( sum_k A[row,k] * W[d,k] ), A:(M,512) W:(512,512) row-major.
// 128x128 tile, BK=16, 256 threads, 8x8 split micro-tile (4+4, 64 apart).
// blockIdx.z in {0,1,2} selects (W, bn, C) triple -> fused QKV dispatch.
__global__ __launch_bounds__(256)
void gemm_bn_kernel(const float* __restrict__ A,
                    const float* __restrict__ W0, const float* __restrict__ W1,
                    const float* __restrict__ W2,
                    const float* __restrict__ g0, const float* __restrict__ b0,
                    const float* __restrict__ m0, const float* __restrict__ v0,
                    const float* __restrict__ g1, const float* __restrict__ b1,
                    const float* __restrict__ m1, const float* __restrict__ v1,
                    const float* __restrict__ g2, const float* __restrict__ b2,
                    const float* __restrict__ m2, const float* __restrict__ v2,
                    float* __restrict__ C0, float* __restrict__ C1,
                    float* __restrict__ C2) {
    const int z = blockIdx.z;
    const float* W  = (z == 0) ? W0 : (z == 1) ? W1 : W2;
    const float* g  = (z == 0) ? g0 : (z == 1) ? g1 : g2;
    const float* bb = (z == 0) ? b0 : (z == 1) ? b1 : b2;
    const float* mm = (z == 0) ? m0 : (z == 1) ? m1 : m2;
    const float* vv = (z == 0) ? v0 : (z == 1) ? v1 : v2;
    float* C        = (z == 0) ? C0 : (z == 1) ? C1 : C2;

    __shared__ float sA[16][132];   // [k][row], pad 132 (2-way max on stores)
    __shared__ float sB[16][132];   // [k][col]
    const int tid = threadIdx.x;
    const int tx = tid & 15, ty = tid >> 4;
    const int row0 = blockIdx.x * 128;
    const int col0 = blockIdx.y * 128;
    const int lr = tid >> 2;          // 0..63
    const int lk = (tid & 3) * 4;     // 0,4,8,12

    const float* Ap0 = A + (size_t)(row0 + lr) * D_ + lk;
    const float* Ap1 = A + (size_t)(row0 + lr + 64) * D_ + lk;
    const float* Wp0 = W + (size_t)(col0 + lr) * D_ + lk;
    const float* Wp1 = W + (size_t)(col0 + lr + 64) * D_ + lk;

    float acc[8][8] = {};
    for (int k0 = 0; k0 < D_; k0 += 16) {
        float4 a0 = *(const float4*)(Ap0 + k0);
        float4 a1 = *(const float4*)(Ap1 + k0);
        float4 w0 = *(const float4*)(Wp0 + k0);
        float4 w1 = *(const float4*)(Wp1 + k0);
        __syncthreads();   // previous iteration done reading LDS
        sA[lk + 0][lr] = a0.x; sA[lk + 1][lr] = a0.y;
        sA[lk + 2][lr] = a0.z; sA[lk + 3][lr] = a0.w;
        sA[lk + 0][lr + 64] = a1.x; sA[lk + 1][lr + 64] = a1.y;
        sA[lk + 2][lr + 64] = a1.z; sA[lk + 3][lr + 64] = a1.w;
        sB[lk + 0][lr] = w0.x; sB[lk + 1][lr] = w0.y;
        sB[lk + 2][lr] = w0.z; sB[lk + 3][lr] = w0.w;
        sB[lk + 0][lr + 64] = w1.x; sB[lk + 1][lr + 64] = w1.y;
        sB[lk + 2][lr + 64] = w1.z; sB[lk + 3][lr + 64] = w1.w;
        __syncthreads();
#pragma unroll
        for (int kk = 0; kk < 16; ++kk) {
            float4 va0 = *(const float4*)&sA[kk][ty * 4];
            float4 va1 = *(const float4*)&sA[kk][64 + ty * 4];
            float4 vb0 = *(const float4*)&sB[kk][tx * 4];
            float4 vb1 = *(const float4*)&sB[kk][64 + tx * 4];
            float ar[8] = {va0.x, va0.y, va0.z, va0.w, va1.x, va1.y, va1.z, va1.w};
            float br[8] = {vb0.x, vb0.y, vb0.z, vb0.w, vb1.x, vb1.y, vb1.z, vb1.w};
#pragma unroll
            for (int i = 0; i < 8; ++i)
#pragma unroll
                for (int j = 0; j < 8; ++j)
                    acc[i][j] += ar[i] * br[j];
        }
    }
    // BN epilogue (per output column d)
    float gg[8], bv[8], mv[8], rv[8];
#pragma unroll
    for (int j = 0; j < 8; ++j) {
        int d = col0 + (j >> 2) * 64 + tx * 4 + (j & 3);
        gg[j] = g[d]; bv[j] = bb[d]; mv[j] = mm[d];
        rv[j] = 1.0f / sqrtf(vv[d] + 1e-5f);
    }
#pragma unroll
    for (int i = 0; i < 8; ++i) {
        int r = row0 + (i >> 2) * 64 + ty * 4 + (i & 3);
#pragma unroll
        for (int cg = 0; cg < 2; ++cg) {
            float4 o;
            o.x = gg[cg*4+0] * (acc[i][cg*4+0] - mv[cg*4+0]) * rv[cg*4+0] + bv[cg*4+0];
            o.y = gg[cg*4+1] * (acc[i][cg*4+1] - mv[cg*4+1]) * rv[cg*4+1] + bv[cg*4+1];
            o.z = gg[cg*4+2] * (acc[i][cg*4+2] - mv[cg*4+2]) * rv[cg*4+2] + bv[cg*4+2];
            o.w = gg[cg*4+3] * (acc[i][cg*4+3] - mv[cg*4+3]) * rv[cg*4+3] + bv[cg*4+3];
            *(float4*)(C + (size_t)r * D_ + col0 + cg * 64 + tx * 4) = o;
        }
    }
}

// LIF over T for three buffers in-place (blockIdx.y selects buffer).
__global__ __launch_bounds__(256)
void lif3_kernel(float* __restrict__ q, float* __restrict__ k, float* __restrict__ v) {
    float* p = (blockIdx.y == 0) ? q : (blockIdx.y == 1) ? k : v;
    size_t i = ((size_t)blockIdx.x * 256 + threadIdx.x) * 4;
    float vm[4] = {0.f, 0.f, 0.f, 0.f};
#pragma unroll
    for (int t = 0; t < T_; ++t) {
        float4 u4 = *(const float4*)(p + (size_t)t * E_ + i);
        float u[4] = {u4.x, u4.y, u4.z, u4.w};
        float4 o;
        o.x = lif_step(vm[0], u[0]);
        o.y = lif_step(vm[1], u[1]);
        o.z = lif_step(vm[2], u[2]);
        o.w = lif_step(vm[3], u[3]);
        *(float4*)(p + (size_t)t * E_ + i) = o;
    }
}

// Attention: per (tb, h, n-tile of 64): Out = (Q K^T * scale + bias) V
// Q,K,V rows are 64 contiguous floats at [ (tb*N+n)*D + h*64 ].
// Out may alias Sq: each block reads only its own (n-tile, h) Q slice (staged
// to LDS at kernel start) and writes exactly that region at the end.
__global__ __launch_bounds__(256)
void attn_kernel(const float* __restrict__ Sq, const float* __restrict__ Sk,
                 const float* __restrict__ Sv, const float* __restrict__ bias_table,
                 float* __restrict__ Out) {
    __shared__ float sQ[64][68];    // [dh][row]
    __shared__ float sKS[64][68];   // [dh][col], reused as S^T: [m][row]
    __shared__ float sV[64][68];    // [m][dh]
    const int tid = threadIdx.x;
    const int tx = tid & 15, ty = tid >> 4;
    const int n0 = blockIdx.x * 64;
    const int h  = blockIdx.y;
    const int tb = blockIdx.z;
    const float scale = 0.044194173824159216f;  // 1/sqrt(512)

    const int lr = tid >> 2;
    const int lc = (tid & 3) * 4;
    {
        const float* qp = Sq + (size_t)(tb * N_ + n0 + lr) * D_ + h * DH_ + lc;
        float4 qv = *(const float4*)qp;
        sQ[lc + 0][lr] = qv.x; sQ[lc + 1][lr] = qv.y;
        sQ[lc + 2][lr] = qv.z; sQ[lc + 3][lr] = qv.w;
    }
    float acc[4][4] = {};
    for (int m0 = 0; m0 < N_; m0 += 64) {
        const float* kp = Sk + (size_t)(tb * N_ + m0 + lr) * D_ + h * DH_ + lc;
        const float* vp = Sv + (size_t)(tb * N_ + m0 + lr) * D_ + h * DH_ + lc;
        float4 kv = *(const float4*)kp;
        float4 vv = *(const float4*)vp;
        __syncthreads();   // prev iter done reading sKS/sV (and Q store visible, iter 0)
        sKS[lc + 0][lr] = kv.x; sKS[lc + 1][lr] = kv.y;
        sKS[lc + 2][lr] = kv.z; sKS[lc + 3][lr] = kv.w;
        *(float4*)&sV[lr][lc] = vv;
        __syncthreads();
        // S = Q K^T  (4x4 per thread; rows ty*4+i, cols tx*4+j)
        float sacc[4][4] = {};
#pragma unroll
        for (int dh = 0; dh < 64; ++dh) {
            float4 a = *(const float4*)&sQ[dh][ty * 4];
            float4 b = *(const float4*)&sKS[dh][tx * 4];
            float ar[4] = {a.x, a.y, a.z, a.w};
            float br[4] = {b.x, b.y, b.z, b.w};
#pragma unroll
            for (int i = 0; i < 4; ++i)
#pragma unroll
                for (int j = 0; j < 4; ++j)
                    sacc[i][j] += ar[i] * br[j];
        }
        __syncthreads();   // all threads done reading sKS as K
        // store S^T (scale + rel-pos bias) into sKS: sKS[m_local][row]
#pragma unroll
        for (int j = 0; j < 4; ++j) {
            int mcol = m0 + tx * 4 + j;
            float4 o;
            float* op = &o.x;
#pragma unroll
            for (int i = 0; i < 4; ++i) {
                int nrow = n0 + ty * 4 + i;
                op[i] = sacc[i][j] * scale +
                        bias_table[(size_t)(mcol - nrow + N_ - 1) * H_ + h];
            }
            *(float4*)&sKS[tx * 4 + j][ty * 4] = o;
        }
        __syncthreads();
        // acc += S V   (S[i][m] = sKS[m][i])
#pragma unroll
        for (int m = 0; m < 64; ++m) {
            float4 a = *(const float4*)&sKS[m][ty * 4];
            float4 b = *(const float4*)&sV[m][tx * 4];
            float ar[4] = {a.x, a.y, a.z, a.w};
            float br[4] = {b.x, b.y, b.z, b.w};
#pragma unroll
            for (int i = 0; i < 4; ++i)
#pragma unroll
                for (int j = 0; j < 4; ++j)
                    acc[i][j] += ar[i] * br[j];
        }
    }
#pragma unroll
    for (int i = 0; i < 4; ++i) {
        int n = n0 + ty * 4 + i;
        float4 o = {acc[i][0], acc[i][1], acc[i][2], acc[i][3]};
        *(float4*)(Out + (size_t)(tb * N_ + n) * D_ + h * DH_ + tx * 4) = o;
    }
}

// LIF over T + gating: out = spk * gate_scale[d] + gate_shift[d], in-place.
__global__ __launch_bounds__(256)
void lif_gate_kernel(float* __restrict__ X, const float* __restrict__ gs,
                     const float* __restrict__ gb) {
    size_t i = ((size_t)blockIdx.x * 256 + threadIdx.x) * 4;
    int d = (int)(i % D_);
    float4 g4 = *(const float4*)(gs + d);
    float4 b4 = *(const float4*)(gb + d);
    float vm[4] = {0.f, 0.f, 0.f, 0.f};
#pragma unroll
    for (int t = 0; t < T_; ++t) {
        float4 u4 = *(const float4*)(X + (size_t)t * E_ + i);
        float u[4] = {u4.x, u4.y, u4.z, u4.w};
        float4 o;
        o.x = lif_step(vm[0], u[0]) * g4.x + b4.x;
        o.y = lif_step(vm[1], u[1]) * g4.y + b4.y;
        o.z = lif_step(vm[2], u[2]) * g4.z + b4.z;
        o.w = lif_step(vm[3], u[3]) * g4.w + b4.w;
        *(float4*)(X + (size_t)t * E_ + i) = o;
    }
}

// Final LIF over T, writes binary spikes (f32) to d_out.
__global__ __launch_bounds__(256)
void lif_out_kernel(const float* __restrict__ X, float* __restrict__ Out) {
    size_t i = ((size_t)blockIdx.x * 256 + threadIdx.x) * 4;
    float vm[4] = {0.f, 0.f, 0.f, 0.f};
#pragma unroll
    for (int t = 0; t < T_; ++t) {
        float4 u4 = *(const float4*)(X + (size_t)t * E_ + i);
        float u[4] = {u4.x, u4.y, u4.z, u4.w};
        float4 o;
        o.x = lif_step(vm[0], u[0]);
        o.y = lif_step(vm[1], u[1]);
        o.z = lif_step(vm[2], u[2]);
        o.w = lif_step(vm[3], u[3]);
        *(float4*)(Out + (size_t)t * E_ + i) = o;
    }
}

extern "C" void kernel_launch(void* const* d_in, const int* in_sizes, int n_in,
                              void* d_out, int out_size, void* d_ws, size_t ws_size,
                              hipStream_t stream) {
    const float* x     = (const float*)d_in[0];
    const float* Wq    = (const float*)d_in[1];
    const float* bnq_g = (const float*)d_in[2];
    const float* bnq_b = (const float*)d_in[3];
    const float* bnq_m = (const float*)d_in[4];
    const float* bnq_v = (const float*)d_in[5];
    const float* Wk    = (const float*)d_in[6];
    const float* bnk_g = (const float*)d_in[7];
    const float* bnk_b = (const float*)d_in[8];
    const float* bnk_m = (const float*)d_in[9];
    const float* bnk_v = (const float*)d_in[10];
    const float* Wv    = (const float*)d_in[11];
    const float* bnv_g = (const float*)d_in[12];
    const float* bnv_b = (const float*)d_in[13];
    const float* bnv_m = (const float*)d_in[14];
    const float* bnv_v = (const float*)d_in[15];
    const float* Wp    = (const float*)d_in[16];
    const float* bnp_g = (const float*)d_in[17];
    const float* bnp_b = (const float*)d_in[18];
    const float* bnp_m = (const float*)d_in[19];
    const float* bnp_v = (const float*)d_in[20];
    const float* bias_table = (const float*)d_in[21];
    const float* gate_scale = (const float*)d_in[22];
    const float* gate_shift = (const float*)d_in[23];

    const size_t BUF = (size_t)T_ * B_ * N_ * D_;  // 8388608 elements
    float* ws = (float*)d_ws;
    float* Uq = ws;             // q preact -> q spikes -> attn out -> gated (in place)
    float* Uk = ws + BUF;       // k preact -> k spikes; later proj preact
    float* Uv = ws + 2 * BUF;   // v preact -> v spikes

    dim3 qkv_grid(M_ / 128, D_ / 128, 3);   // (128, 4, 3)
    dim3 proj_grid(M_ / 128, D_ / 128, 1);
    dim3 ew_grid(2048);                     // 2048*256*4 = E_ elements per slab

    // Q,K,V preactivations (fused GEMM+BN, one dispatch)
    gemm_bn_kernel<<<qkv_grid, 256, 0, stream>>>(
        x, Wq, Wk, Wv,
        bnq_g, bnq_b, bnq_m, bnq_v,
        bnk_g, bnk_b, bnk_m, bnk_v,
        bnv_g, bnv_b, bnv_m, bnv_v,
        Uq, Uk, Uv);
    lif3_kernel<<<dim3(2048, 3), 256, 0, stream>>>(Uq, Uk, Uv);
    // attention, output in place over Uq
    attn_kernel<<<dim3(N_ / 64, H_, T_ * B_), 256, 0, stream>>>(
        Uq, Uk, Uv, bias_table, Uq);
    lif_gate_kernel<<<ew_grid, 256, 0, stream>>>(Uq, gate_scale, gate_shift);
    // projection GEMM+BN (same kernel, z=1 grid, pointers replicated)
    gemm_bn_kernel<<<proj_grid, 256, 0, stream>>>(
        Uq, Wp, Wp, Wp,
        bnp_g, bnp_b, bnp_m, bnp_v,
        bnp_g, bnp_b, bnp_m, bnp_v,
        bnp_g, bnp_b, bnp_m, bnp_v,
        Uk, Uk, Uk);
    lif_out_kernel<<<ew_grid, 256, 0, stream>>>(Uk, (float*)d_out);
}

// Round 4
// 589.638 us; speedup vs baseline: 1.3666x; 1.3666x over previous
//
#include <hip/hip_runtime.h>

// SSA pipeline, round 4 (= round 3 resubmit; broker timeout, never ran).
// Exact binary-spike MFMA for attention + proj GEMM.
// Shapes: T=4 B=8 N=512 D=512 H=8 DH=64.  M = T*B*N = 16384.
// ws: 3 x BUF f32 buffers (100.7 MB), Uk region reused for bf16 spikes/W3/offset.

#define T_  4
#define B_  8
#define N_  512
#define D_  512
#define H_  8
#define DH_ 64
#define M_  (T_ * B_ * N_)
#define E_  ((size_t)B_ * N_ * D_)

typedef __attribute__((ext_vector_type(8))) short bf16x8;
typedef __attribute__((ext_vector_type(4))) float f32x4;
typedef __attribute__((ext_vector_type(8))) unsigned short us8;

__device__ __forceinline__ float lif_step(float& vmem, float u) {
    vmem += (u - vmem) * 0.5f;                 // TAU = 2.0
    float spk = (vmem >= 1.0f) ? 1.0f : 0.0f;
    vmem *= (1.0f - spk);
    return spk;
}
__device__ __forceinline__ ushort bf16_rne(float f) {
    unsigned u = __float_as_uint(f);
    return (ushort)((u + 0x7FFFu + ((u >> 16) & 1u)) >> 16);
}
__device__ __forceinline__ float bf16_f(ushort h) {
    return __uint_as_float(((unsigned)h) << 16);
}
__device__ __forceinline__ ushort spike_bits(float v) {   // v is exactly 0.0 or 1.0
    return (v != 0.0f) ? (ushort)0x3F80 : (ushort)0;
}

// ---------------- f32 QKV GEMM + BN (proven round 2) --------------------------
__global__ __launch_bounds__(256)
void gemm_bn_kernel(const float* __restrict__ A,
                    const float* __restrict__ W0, const float* __restrict__ W1,
                    const float* __restrict__ W2,
                    const float* __restrict__ g0, const float* __restrict__ b0,
                    const float* __restrict__ m0, const float* __restrict__ v0,
                    const float* __restrict__ g1, const float* __restrict__ b1,
                    const float* __restrict__ m1, const float* __restrict__ v1,
                    const float* __restrict__ g2, const float* __restrict__ b2,
                    const float* __restrict__ m2, const float* __restrict__ v2,
                    float* __restrict__ C0, float* __restrict__ C1,
                    float* __restrict__ C2) {
    const int z = blockIdx.z;
    const float* W  = (z == 0) ? W0 : (z == 1) ? W1 : W2;
    const float* g  = (z == 0) ? g0 : (z == 1) ? g1 : g2;
    const float* bb = (z == 0) ? b0 : (z == 1) ? b1 : b2;
    const float* mm = (z == 0) ? m0 : (z == 1) ? m1 : m2;
    const float* vv = (z == 0) ? v0 : (z == 1) ? v1 : v2;
    float* C        = (z == 0) ? C0 : (z == 1) ? C1 : C2;

    __shared__ float sA[16][132];
    __shared__ float sB[16][132];
    const int tid = threadIdx.x;
    const int tx = tid & 15, ty = tid >> 4;
    const int row0 = blockIdx.x * 128;
    const int col0 = blockIdx.y * 128;
    const int lr = tid >> 2;
    const int lk = (tid & 3) * 4;

    const float* Ap0 = A + (size_t)(row0 + lr) * D_ + lk;
    const float* Ap1 = A + (size_t)(row0 + lr + 64) * D_ + lk;
    const float* Wp0 = W + (size_t)(col0 + lr) * D_ + lk;
    const float* Wp1 = W + (size_t)(col0 + lr + 64) * D_ + lk;

    float acc[8][8] = {};
    for (int k0 = 0; k0 < D_; k0 += 16) {
        float4 a0 = *(const float4*)(Ap0 + k0);
        float4 a1 = *(const float4*)(Ap1 + k0);
        float4 w0 = *(const float4*)(Wp0 + k0);
        float4 w1 = *(const float4*)(Wp1 + k0);
        __syncthreads();
        sA[lk + 0][lr] = a0.x; sA[lk + 1][lr] = a0.y;
        sA[lk + 2][lr] = a0.z; sA[lk + 3][lr] = a0.w;
        sA[lk + 0][lr + 64] = a1.x; sA[lk + 1][lr + 64] = a1.y;
        sA[lk + 2][lr + 64] = a1.z; sA[lk + 3][lr + 64] = a1.w;
        sB[lk + 0][lr] = w0.x; sB[lk + 1][lr] = w0.y;
        sB[lk + 2][lr] = w0.z; sB[lk + 3][lr] = w0.w;
        sB[lk + 0][lr + 64] = w1.x; sB[lk + 1][lr + 64] = w1.y;
        sB[lk + 2][lr + 64] = w1.z; sB[lk + 3][lr + 64] = w1.w;
        __syncthreads();
#pragma unroll
        for (int kk = 0; kk < 16; ++kk) {
            float4 va0 = *(const float4*)&sA[kk][ty * 4];
            float4 va1 = *(const float4*)&sA[kk][64 + ty * 4];
            float4 vb0 = *(const float4*)&sB[kk][tx * 4];
            float4 vb1 = *(const float4*)&sB[kk][64 + tx * 4];
            float ar[8] = {va0.x, va0.y, va0.z, va0.w, va1.x, va1.y, va1.z, va1.w};
            float br[8] = {vb0.x, vb0.y, vb0.z, vb0.w, vb1.x, vb1.y, vb1.z, vb1.w};
#pragma unroll
            for (int i = 0; i < 8; ++i)
#pragma unroll
                for (int j = 0; j < 8; ++j)
                    acc[i][j] += ar[i] * br[j];
        }
    }
    float gg[8], bv[8], mv[8], rv[8];
#pragma unroll
    for (int j = 0; j < 8; ++j) {
        int d = col0 + (j >> 2) * 64 + tx * 4 + (j & 3);
        gg[j] = g[d]; bv[j] = bb[d]; mv[j] = mm[d];
        rv[j] = 1.0f / sqrtf(vv[d] + 1e-5f);
    }
#pragma unroll
    for (int i = 0; i < 8; ++i) {
        int r = row0 + (i >> 2) * 64 + ty * 4 + (i & 3);
#pragma unroll
        for (int cg = 0; cg < 2; ++cg) {
            float4 o;
            o.x = gg[cg*4+0] * (acc[i][cg*4+0] - mv[cg*4+0]) * rv[cg*4+0] + bv[cg*4+0];
            o.y = gg[cg*4+1] * (acc[i][cg*4+1] - mv[cg*4+1]) * rv[cg*4+1] + bv[cg*4+1];
            o.z = gg[cg*4+2] * (acc[i][cg*4+2] - mv[cg*4+2]) * rv[cg*4+2] + bv[cg*4+2];
            o.w = gg[cg*4+3] * (acc[i][cg*4+3] - mv[cg*4+3]) * rv[cg*4+3] + bv[cg*4+3];
            *(float4*)(C + (size_t)r * D_ + col0 + cg * 64 + tx * 4) = o;
        }
    }
}

// ---------------- LIF over T for q,k,v (f32 -> f32 spikes, in place) ----------
__global__ __launch_bounds__(256)
void lif3_kernel(float* __restrict__ q, float* __restrict__ k, float* __restrict__ v) {
    float* p = (blockIdx.y == 0) ? q : (blockIdx.y == 1) ? k : v;
    size_t i = ((size_t)blockIdx.x * 256 + threadIdx.x) * 4;
    float vm[4] = {0.f, 0.f, 0.f, 0.f};
#pragma unroll
    for (int t = 0; t < T_; ++t) {
        float4 u4 = *(const float4*)(p + (size_t)t * E_ + i);
        float4 o;
        o.x = lif_step(vm[0], u4.x);
        o.y = lif_step(vm[1], u4.y);
        o.z = lif_step(vm[2], u4.z);
        o.w = lif_step(vm[3], u4.w);
        *(float4*)(p + (size_t)t * E_ + i) = o;
    }
}

// ---------------- attention via exact MFMA -----------------------------------
// Per (tb, h, n-tile 64). out = scale*(S@V) + (Toeplitz-bias @ V), S = Q@K^T.
// Q,K,V are binary spikes; S integer<=64 (bf16-exact); bias via 3-split bf16.
__global__ __launch_bounds__(256)
void attn_mfma_kernel(const float* __restrict__ Sq, const float* __restrict__ Sk,
                      const float* __restrict__ Sv, const float* __restrict__ table,
                      float* __restrict__ Out) {
    __shared__ __align__(16) ushort sQ[64 * 72];
    __shared__ __align__(16) ushort sK[64 * 72];
    __shared__ __align__(16) ushort sVT[64 * 72 + 32];  // row base d*72 + 8*(d>>4)
    __shared__ __align__(16) ushort sS[64 * 72];
    __shared__ ushort sT3[3][576];
    const int tid = threadIdx.x;
    const int l = tid & 63, w = tid >> 6;
    const int cl = l & 15, g = l >> 4;
    const int n0 = blockIdx.x * 64;
    const int h  = blockIdx.y;
    const int tb = blockIdx.z;

    // stage Q spikes -> bf16  (rows n0..n0+63, cols h*64..)
    {
        const int r = tid >> 2, d0 = (tid & 3) << 4;
        const float* qp = Sq + ((size_t)(tb * N_ + n0 + r)) * D_ + h * DH_ + d0;
        float4 v0 = *(const float4*)(qp);
        float4 v1 = *(const float4*)(qp + 4);
        float4 v2 = *(const float4*)(qp + 8);
        float4 v3 = *(const float4*)(qp + 12);
        us8 a, b;
        a[0]=spike_bits(v0.x); a[1]=spike_bits(v0.y); a[2]=spike_bits(v0.z); a[3]=spike_bits(v0.w);
        a[4]=spike_bits(v1.x); a[5]=spike_bits(v1.y); a[6]=spike_bits(v1.z); a[7]=spike_bits(v1.w);
        b[0]=spike_bits(v2.x); b[1]=spike_bits(v2.y); b[2]=spike_bits(v2.z); b[3]=spike_bits(v2.w);
        b[4]=spike_bits(v3.x); b[5]=spike_bits(v3.y); b[6]=spike_bits(v3.z); b[7]=spike_bits(v3.w);
        *(us8*)&sQ[r * 72 + d0] = a;
        *(us8*)&sQ[r * 72 + d0 + 8] = b;
    }
    // stage 3-split bias table slice: e in [0,575), idx = bbase+e
    const int bbase = 448 - n0;
    for (int e = tid; e < 575; e += 256) {
        float t = table[(size_t)(bbase + e) * H_ + h];
        ushort h0 = bf16_rne(t); float r1 = t - bf16_f(h0);
        ushort h1 = bf16_rne(r1); float r2 = r1 - bf16_f(h1);
        ushort h2 = bf16_rne(r2);
        sT3[0][e] = h0; sT3[1][e] = h1; sT3[2][e] = h2;
    }
    __syncthreads();
    // hoist this wave's Q fragments (rows 16w..16w+15)
    bf16x8 qf0 = *(const bf16x8*)&sQ[(16 * w + cl) * 72 + 8 * g];
    bf16x8 qf1 = *(const bf16x8*)&sQ[(16 * w + cl) * 72 + 32 + 8 * g];

    f32x4 svacc[4], bacc[4];
#pragma unroll
    for (int dt = 0; dt < 4; ++dt) {
        svacc[dt] = (f32x4){0.f, 0.f, 0.f, 0.f};
        bacc[dt]  = (f32x4){0.f, 0.f, 0.f, 0.f};
    }

    for (int m0 = 0; m0 < N_; m0 += 64) {
        __syncthreads();  // prev-iter PV reads done; safe to restage
        {
            const int r = tid >> 2, d0 = (tid & 3) << 4;
            const float* kp = Sk + ((size_t)(tb * N_ + m0 + r)) * D_ + h * DH_ + d0;
            float4 v0 = *(const float4*)(kp);
            float4 v1 = *(const float4*)(kp + 4);
            float4 v2 = *(const float4*)(kp + 8);
            float4 v3 = *(const float4*)(kp + 12);
            us8 a, b;
            a[0]=spike_bits(v0.x); a[1]=spike_bits(v0.y); a[2]=spike_bits(v0.z); a[3]=spike_bits(v0.w);
            a[4]=spike_bits(v1.x); a[5]=spike_bits(v1.y); a[6]=spike_bits(v1.z); a[7]=spike_bits(v1.w);
            b[0]=spike_bits(v2.x); b[1]=spike_bits(v2.y); b[2]=spike_bits(v2.z); b[3]=spike_bits(v2.w);
            b[4]=spike_bits(v3.x); b[5]=spike_bits(v3.y); b[6]=spike_bits(v3.z); b[7]=spike_bits(v3.w);
            *(us8*)&sK[r * 72 + d0] = a;
            *(us8*)&sK[r * 72 + d0 + 8] = b;
            // V staged transposed: sVT[d][m], row base d*72 + 8*(d>>4)
            const float* vp = Sv + ((size_t)(tb * N_ + m0 + r)) * D_ + h * DH_ + d0;
            float4 u0 = *(const float4*)(vp);
            float4 u1 = *(const float4*)(vp + 4);
            float4 u2 = *(const float4*)(vp + 8);
            float4 u3 = *(const float4*)(vp + 12);
            float vals[16] = {u0.x,u0.y,u0.z,u0.w, u1.x,u1.y,u1.z,u1.w,
                              u2.x,u2.y,u2.z,u2.w, u3.x,u3.y,u3.z,u3.w};
            const int vbase = d0 * 72 + ((tid & 3) << 3) + r;
#pragma unroll
            for (int i = 0; i < 16; ++i)
                sVT[vbase + i * 72] = spike_bits(vals[i]);
        }
        __syncthreads();
        // QK^T: wave w computes S rows [16w,16w+16) x 64 m, exact integers
#pragma unroll
        for (int ms = 0; ms < 4; ++ms) {
            bf16x8 kf0 = *(const bf16x8*)&sK[(16 * ms + cl) * 72 + 8 * g];
            bf16x8 kf1 = *(const bf16x8*)&sK[(16 * ms + cl) * 72 + 32 + 8 * g];
            f32x4 s4 = (f32x4){0.f, 0.f, 0.f, 0.f};
            s4 = __builtin_amdgcn_mfma_f32_16x16x32_bf16(qf0, kf0, s4, 0, 0, 0);
            s4 = __builtin_amdgcn_mfma_f32_16x16x32_bf16(qf1, kf1, s4, 0, 0, 0);
#pragma unroll
            for (int q = 0; q < 4; ++q)   // truncation exact: S is small integer
                sS[(16 * w + 4 * g + q) * 72 + 16 * ms + cl] =
                    (ushort)(__float_as_uint(s4[q]) >> 16);
        }
        __syncthreads();
        // PV + bias-Toeplitz, K=32 per step, 2 steps per 64-m chunk
#pragma unroll
        for (int ks = 0; ks < 2; ++ks) {
            const int mk = ks * 32;
            bf16x8 af = *(const bf16x8*)&sS[(16 * w + cl) * 72 + mk + 8 * g];
            const int e0 = m0 + mk + 8 * g - 16 * w - cl + 63;
            bf16x8 t0, t1, t2;
#pragma unroll
            for (int j = 0; j < 8; ++j) {
                t0[j] = (short)sT3[0][e0 + j];
                t1[j] = (short)sT3[1][e0 + j];
                t2[j] = (short)sT3[2][e0 + j];
            }
#pragma unroll
            for (int dt = 0; dt < 4; ++dt) {
                const int dv = 16 * dt + cl;
                bf16x8 vf = *(const bf16x8*)&sVT[dv * 72 + 8 * dt + mk + 8 * g];
                svacc[dt] = __builtin_amdgcn_mfma_f32_16x16x32_bf16(af, vf, svacc[dt], 0, 0, 0);
                bacc[dt]  = __builtin_amdgcn_mfma_f32_16x16x32_bf16(t0, vf, bacc[dt], 0, 0, 0);
                bacc[dt]  = __builtin_amdgcn_mfma_f32_16x16x32_bf16(t1, vf, bacc[dt], 0, 0, 0);
                bacc[dt]  = __builtin_amdgcn_mfma_f32_16x16x32_bf16(t2, vf, bacc[dt], 0, 0, 0);
            }
        }
    }
    const float scale = 0.044194173824159216f;  // 1/sqrt(512)
#pragma unroll
    for (int dt = 0; dt < 4; ++dt)
#pragma unroll
        for (int q = 0; q < 4; ++q) {
            int n = n0 + 16 * w + 4 * g + q;
            int d = 16 * dt + cl;
            Out[((size_t)(tb * N_ + n)) * D_ + h * DH_ + d] =
                scale * svacc[dt][q] + bacc[dt][q];
        }
}

// ---------------- W' = gs (x) Wp, 3-split to bf16 -----------------------------
__global__ __launch_bounds__(256)
void w3_split_kernel(const float* __restrict__ Wp, const float* __restrict__ gs,
                     ushort* __restrict__ W3) {
    int idx = blockIdx.x * 256 + threadIdx.x;   // 0..262143
    int d = idx & (D_ - 1);
    float t = gs[d] * Wp[idx];
    ushort h0 = bf16_rne(t); float r1 = t - bf16_f(h0);
    ushort h1 = bf16_rne(r1); float r2 = r1 - bf16_f(h1);
    ushort h2 = bf16_rne(r2);
    W3[idx] = h0; W3[D_ * D_ + idx] = h1; W3[2 * D_ * D_ + idx] = h2;
}

// offset[c] = sum_d gb[d] * Wp[c][d]
__global__ __launch_bounds__(256)
void offset_kernel(const float* __restrict__ Wp, const float* __restrict__ gb,
                   float* __restrict__ off) {
    int c = blockIdx.x * 256 + threadIdx.x;
    float acc = 0.f;
    for (int d = 0; d < D_; ++d) acc += gb[d] * Wp[(size_t)c * D_ + d];
    off[c] = acc;
}

// LIF over T, write bf16 binary spikes (gate folded into W3/offset)
__global__ __launch_bounds__(256)
void lif_spike_bf16_kernel(const float* __restrict__ X, ushort* __restrict__ S) {
    size_t i = ((size_t)blockIdx.x * 256 + threadIdx.x) * 4;
    float vm[4] = {0.f, 0.f, 0.f, 0.f};
#pragma unroll
    for (int t = 0; t < T_; ++t) {
        float4 u4 = *(const float4*)(X + (size_t)t * E_ + i);
        ushort4 o;
        o.x = spike_bits(lif_step(vm[0], u4.x));
        o.y = spike_bits(lif_step(vm[1], u4.y));
        o.z = spike_bits(lif_step(vm[2], u4.z));
        o.w = spike_bits(lif_step(vm[3], u4.w));
        *(ushort4*)(S + (size_t)t * E_ + i) = o;
    }
}

// ---------------- proj GEMM: binary spikes x 3-split W', BN epilogue ----------
// C[r][c] = bn( sum_s sum_d Sb[r][d]*W3[s][c][d] + off[c] )
__global__ __launch_bounds__(256)
void proj_mfma_kernel(const ushort* __restrict__ Sb, const ushort* __restrict__ W3,
                      const float* __restrict__ off,
                      const float* __restrict__ g, const float* __restrict__ bb,
                      const float* __restrict__ mm, const float* __restrict__ vv,
                      float* __restrict__ C) {
    __shared__ __align__(16) ushort sA[128 * 72];
    __shared__ __align__(16) ushort sB[128 * 72];
    const int tid = threadIdx.x;
    const int l = tid & 63, w = tid >> 6;
    const int cl = l & 15, gq = l >> 4;
    const int row0 = blockIdx.x * 128, col0 = blockIdx.y * 128;

    f32x4 acc[2][8];
#pragma unroll
    for (int rs = 0; rs < 2; ++rs)
#pragma unroll
        for (int cs = 0; cs < 8; ++cs) acc[rs][cs] = (f32x4){0.f, 0.f, 0.f, 0.f};

    for (int k0 = 0; k0 < D_; k0 += 64) {
        __syncthreads();
        {   // stage A chunk (128 rows x 64 d)
            const int r = tid >> 1, hf = (tid & 1) * 32;
            const ushort* ap = Sb + ((size_t)(row0 + r)) * D_ + k0 + hf;
#pragma unroll
            for (int u = 0; u < 4; ++u)
                *(us8*)&sA[r * 72 + hf + 8 * u] = *(const us8*)(ap + 8 * u);
        }
        for (int s = 0; s < 3; ++s) {
            if (s) __syncthreads();
            {   // stage B split chunk (128 cols x 64 d)
                const int r = tid >> 1, hf = (tid & 1) * 32;
                const ushort* bp = W3 + (size_t)s * (D_ * D_) +
                                   ((size_t)(col0 + r)) * D_ + k0 + hf;
#pragma unroll
                for (int u = 0; u < 4; ++u)
                    *(us8*)&sB[r * 72 + hf + 8 * u] = *(const us8*)(bp + 8 * u);
            }
            __syncthreads();
            bf16x8 af[2][2];
#pragma unroll
            for (int rs = 0; rs < 2; ++rs)
#pragma unroll
                for (int kh = 0; kh < 2; ++kh)
                    af[rs][kh] = *(const bf16x8*)&sA[(32 * w + 16 * rs + cl) * 72 +
                                                     32 * kh + 8 * gq];
#pragma unroll
            for (int cs = 0; cs < 8; ++cs) {
#pragma unroll
                for (int kh = 0; kh < 2; ++kh) {
                    bf16x8 bfr = *(const bf16x8*)&sB[(16 * cs + cl) * 72 +
                                                     32 * kh + 8 * gq];
#pragma unroll
                    for (int rs = 0; rs < 2; ++rs)
                        acc[rs][cs] = __builtin_amdgcn_mfma_f32_16x16x32_bf16(
                            af[rs][kh], bfr, acc[rs][cs], 0, 0, 0);
                }
            }
        }
    }
#pragma unroll
    for (int cs = 0; cs < 8; ++cs) {
        int c = col0 + 16 * cs + cl;
        float o = off[c], gg = g[c], bv = bb[c], mv = mm[c];
        float rv = 1.0f / sqrtf(vv[c] + 1e-5f);
#pragma unroll
        for (int rs = 0; rs < 2; ++rs)
#pragma unroll
            for (int q = 0; q < 4; ++q) {
                int r = row0 + 32 * w + 16 * rs + 4 * gq + q;
                float val = acc[rs][cs][q] + o;
                C[(size_t)r * D_ + c] = gg * (val - mv) * rv + bv;
            }
    }
}

// Final LIF over T, writes binary spikes (f32) to d_out.
__global__ __launch_bounds__(256)
void lif_out_kernel(const float* __restrict__ X, float* __restrict__ Out) {
    size_t i = ((size_t)blockIdx.x * 256 + threadIdx.x) * 4;
    float vm[4] = {0.f, 0.f, 0.f, 0.f};
#pragma unroll
    for (int t = 0; t < T_; ++t) {
        float4 u4 = *(const float4*)(X + (size_t)t * E_ + i);
        float4 o;
        o.x = lif_step(vm[0], u4.x);
        o.y = lif_step(vm[1], u4.y);
        o.z = lif_step(vm[2], u4.z);
        o.w = lif_step(vm[3], u4.w);
        *(float4*)(Out + (size_t)t * E_ + i) = o;
    }
}

extern "C" void kernel_launch(void* const* d_in, const int* in_sizes, int n_in,
                              void* d_out, int out_size, void* d_ws, size_t ws_size,
                              hipStream_t stream) {
    const float* x     = (const float*)d_in[0];
    const float* Wq    = (const float*)d_in[1];
    const float* bnq_g = (const float*)d_in[2];
    const float* bnq_b = (const float*)d_in[3];
    const float* bnq_m = (const float*)d_in[4];
    const float* bnq_v = (const float*)d_in[5];
    const float* Wk    = (const float*)d_in[6];
    const float* bnk_g = (const float*)d_in[7];
    const float* bnk_b = (const float*)d_in[8];
    const float* bnk_m = (const float*)d_in[9];
    const float* bnk_v = (const float*)d_in[10];
    const float* Wv    = (const float*)d_in[11];
    const float* bnv_g = (const float*)d_in[12];
    const float* bnv_b = (const float*)d_in[13];
    const float* bnv_m = (const float*)d_in[14];
    const float* bnv_v = (const float*)d_in[15];
    const float* Wp    = (const float*)d_in[16];
    const float* bnp_g = (const float*)d_in[17];
    const float* bnp_b = (const float*)d_in[18];
    const float* bnp_m = (const float*)d_in[19];
    const float* bnp_v = (const float*)d_in[20];
    const float* bias_table = (const float*)d_in[21];
    const float* gate_scale = (const float*)d_in[22];
    const float* gate_shift = (const float*)d_in[23];

    const size_t BUF = (size_t)T_ * B_ * N_ * D_;  // 8388608
    float* ws = (float*)d_ws;
    float* Uq = ws;               // q preact -> q spikes -> attn out (in place)
    float* Uk = ws + BUF;         // k preact -> k spikes; region reused after attn
    float* Uv = ws + 2 * BUF;     // v preact -> v spikes; then proj preact
    ushort* Sb = (ushort*)Uk;                                  // BUF bf16 spikes
    ushort* W3 = (ushort*)(Uk + BUF / 2 + BUF / 4);            // 3*512*512 bf16
    float*  off = Uk + BUF / 2 + BUF / 4 + (3 * D_ * D_) / 2 + 64;

    dim3 qkv_grid(M_ / 128, D_ / 128, 3);
    dim3 ew_grid(2048);

    gemm_bn_kernel<<<qkv_grid, 256, 0, stream>>>(
        x, Wq, Wk, Wv,
        bnq_g, bnq_b, bnq_m, bnq_v,
        bnk_g, bnk_b, bnk_m, bnk_v,
        bnv_g, bnv_b, bnv_m, bnv_v,
        Uq, Uk, Uv);
    lif3_kernel<<<dim3(2048, 3), 256, 0, stream>>>(Uq, Uk, Uv);
    attn_mfma_kernel<<<dim3(N_ / 64, H_, T_ * B_), 256, 0, stream>>>(
        Uq, Uk, Uv, bias_table, Uq);
    w3_split_kernel<<<dim3(1024), 256, 0, stream>>>(Wp, gate_scale, W3);
    offset_kernel<<<dim3(2), 256, 0, stream>>>(Wp, gate_shift, off);
    lif_spike_bf16_kernel<<<ew_grid, 256, 0, stream>>>(Uq, Sb);
    proj_mfma_kernel<<<dim3(M_ / 128, D_ / 128), 256, 0, stream>>>(
        Sb, W3, off, bnp_g, bnp_b, bnp_m, bnp_v, Uv);
    lif_out_kernel<<<ew_grid, 256, 0, stream>>>(Uv, (float*)d_out);
}